// Round 1
// 1524.338 us; speedup vs baseline: 1.3951x; 1.3951x over previous
//
#include <hip/hip_runtime.h>

// ---------------------------------------------------------------------------
// GenomeDecoder: transformer encoder (tiny) -> 1028 sequential GRU steps ->
// output chunks.  Chunk feedback folded into recurrence (A = Wih@out_W
// absorbed), r/z gate rows pre-summed -> one 1024x256 matvec per step.
// R3: INT8 weight matrix (per-row scale) + v_dot4_i32_i8 -> 128 dot instrs
// per step (vs 256 fdot2), all 8 weight slices in 128 arch VGPRs (no AGPR
// copies, no weight LDS traffic), exact int32 quad-reduce, and raw s_barrier
// (lgkmcnt-only) so per-step global h stores never drain vmcnt on the
// critical path.  |h| < 1 strictly (tanh-gated mixing) => fixed h scale 127.
// ---------------------------------------------------------------------------

typedef unsigned int uint_t;

// ---- workspace layout (4-byte slot indices) ----
static constexpr size_t WS_HB   = 0;        // 16*16*256
static constexpr size_t WS_QKV  = 65536;    // 16*16*768
static constexpr size_t WS_AO   = 262144;   // 16*16*256
static constexpr size_t WS_F1   = 327680;   // 16*16*1024
static constexpr size_t WS_LAT  = 589824;   // 16*256
static constexpr size_t WS_GI0  = 593920;   // 16*768
static constexpr size_t WS_CV   = 606208;   // 1024 fused-bias consts
static constexpr size_t WS_MS   = 607232;   // 1024 per-row scales (rowmax/127^2)
static constexpr size_t WS_M8   = 608256;   // 1024*64 dwords of packed int8 M
static constexpr size_t WS_HSEQ = 673792;   // 1028*16*256 floats

#if defined(__has_builtin)
#if __has_builtin(__builtin_amdgcn_sdot4)
#define HAVE_SDOT4 1
#endif
#endif

__device__ inline int SDOT4(uint_t a, uint_t b, int c){
#ifdef HAVE_SDOT4
    return __builtin_amdgcn_sdot4((int)a, (int)b, c, false);
#else
    int r = c;
    r += (int)(signed char)(a      ) * (int)(signed char)(b      );
    r += (int)(signed char)(a >>  8) * (int)(signed char)(b >>  8);
    r += (int)(signed char)(a >> 16) * (int)(signed char)(b >> 16);
    r += (int)(signed char)(a >> 24) * (int)(signed char)(b >> 24);
    return r;
#endif
}

__device__ inline float sigf(float x){ return 1.0f/(1.0f+__expf(-x)); }
__device__ inline float tanh_fast(float x){ float e=__expf(2.0f*x); return (e-1.0f)/(e+1.0f); }

// exact int quad reduction on the VALU pipe (DPP quad_perm); lanes 4k..4k+3
// share one row-group g, so xor-1 + xor-2 sums the quad.
__device__ inline int quad_reduce_add_i(int a){
    int t = __builtin_amdgcn_update_dpp(0, a, 0xB1, 0xF, 0xF, false); // xor 1
    a += t;
    t = __builtin_amdgcn_update_dpp(0, a, 0x4E, 0xF, 0xF, false);     // xor 2
    return a + t;
}

// ======================= transformer front-end =============================

__global__ __launch_bounds__(256) void k_embed(const float* gs, const float* eW,
                                               const float* eb, float* ws){
    int bs = blockIdx.x;            // b*16+s
    int i  = threadIdx.x;
    const float* g = gs + bs*16;
    float acc = eb[i];
#pragma unroll
    for(int d=0; d<16; ++d) acc += g[d]*eW[i*16+d];
    ws[WS_HB + (size_t)bs*256 + i] = acc;
}

__global__ __launch_bounds__(256) void k_qkv(const float* qkvW, const float* qkvb,
                                             float* ws, int l){
    __shared__ float hr[16][256];
    int b = blockIdx.x, jc = blockIdx.y;
    for(int idx=threadIdx.x; idx<4096; idx+=256)
        hr[idx>>8][idx&255] = ws[WS_HB + (size_t)(b*16+(idx>>8))*256 + (idx&255)];
    __syncthreads();
    int j = jc*256 + threadIdx.x;
    float bias = qkvb[l*768 + j];
    float acc[16];
#pragma unroll
    for(int s=0;s<16;++s) acc[s]=bias;
    const float* wr = qkvW + (size_t)(l*768 + j)*256;
    for(int k=0;k<256;k+=4){
        float4 w4 = *(const float4*)(wr+k);
#pragma unroll
        for(int s=0;s<16;++s)
            acc[s] += w4.x*hr[s][k] + w4.y*hr[s][k+1] + w4.z*hr[s][k+2] + w4.w*hr[s][k+3];
    }
    for(int s=0;s<16;++s) ws[WS_QKV + (size_t)(b*16+s)*768 + j] = acc[s];
}

__global__ __launch_bounds__(256) void k_attn(float* ws){
    __shared__ float ql[16][64], kl[16][64], vl[16][64], sc[16][16];
    int b = blockIdx.x>>2, hh = blockIdx.x&3;
    for(int idx=threadIdx.x; idx<1024; idx+=256){
        int s_=idx>>6, d=idx&63;
        const float* base = &ws[WS_QKV + (size_t)(b*16+s_)*768 + hh*64 + d];
        ql[s_][d]=base[0]; kl[s_][d]=base[256]; vl[s_][d]=base[512];
    }
    __syncthreads();
    int s = threadIdx.x>>4, t = threadIdx.x&15;
    float a=0.f;
#pragma unroll
    for(int d=0; d<64; ++d) a += ql[s][d]*kl[t][d];
    sc[s][t] = a*0.125f;
    __syncthreads();
    if(threadIdx.x<16){
        int r=threadIdx.x;
        float m=-1e30f;
#pragma unroll
        for(int tt=0;tt<16;++tt) m=fmaxf(m,sc[r][tt]);
        float e[16]; float sum=0.f;
#pragma unroll
        for(int tt=0;tt<16;++tt){ e[tt]=__expf(sc[r][tt]-m); sum+=e[tt]; }
        float inv=1.0f/sum;
#pragma unroll
        for(int tt=0;tt<16;++tt) sc[r][tt]=e[tt]*inv;
    }
    __syncthreads();
    int dg = (threadIdx.x&15)*4;
#pragma unroll
    for(int dd=0;dd<4;++dd){
        int d = dg+dd; float o=0.f;
#pragma unroll
        for(int tt=0;tt<16;++tt) o += sc[s][tt]*vl[tt][d];
        ws[WS_AO + (size_t)(b*16+s)*256 + hh*64 + d] = o;
    }
}

__global__ __launch_bounds__(256) void k_ao_ln(const float* aoW, const float* aob,
                                               const float* g1, const float* b1,
                                               float* ws, int l){
    __shared__ float ao[256]; __shared__ float red[256];
    int bs = blockIdx.x, i = threadIdx.x;
    ao[i] = ws[WS_AO + (size_t)bs*256 + i];
    __syncthreads();
    const float* wr = aoW + (size_t)(l*256+i)*256;
    float acc = aob[l*256+i];
    for(int k=0;k<256;k+=4){
        float4 w4 = *(const float4*)(wr+k);
        acc += w4.x*ao[k]+w4.y*ao[k+1]+w4.z*ao[k+2]+w4.w*ao[k+3];
    }
    float x = ws[WS_HB + (size_t)bs*256 + i] + acc;
    red[i]=x; __syncthreads();
    for(int off=128;off>0;off>>=1){ if(i<off) red[i]+=red[i+off]; __syncthreads(); }
    float m = red[0]*(1.0f/256.0f); __syncthreads();
    float d = x-m;
    red[i]=d*d; __syncthreads();
    for(int off=128;off>0;off>>=1){ if(i<off) red[i]+=red[i+off]; __syncthreads(); }
    float v = red[0]*(1.0f/256.0f);
    float y = d / sqrtf(v+1e-5f);
    ws[WS_HB + (size_t)bs*256 + i] = y*g1[l*256+i] + b1[l*256+i];
}

__global__ __launch_bounds__(256) void k_ffn1(const float* W1, const float* fb1,
                                              float* ws, int l){
    __shared__ float hr[16][256];
    int b = blockIdx.x, jc = blockIdx.y;
    for(int idx=threadIdx.x; idx<4096; idx+=256)
        hr[idx>>8][idx&255] = ws[WS_HB + (size_t)(b*16+(idx>>8))*256 + (idx&255)];
    __syncthreads();
    int j = jc*256 + threadIdx.x;
    float bias = fb1[l*1024+j];
    float acc[16];
#pragma unroll
    for(int s=0;s<16;++s) acc[s]=bias;
    const float* wr = W1 + (size_t)(l*1024+j)*256;
    for(int k=0;k<256;k+=4){
        float4 w4 = *(const float4*)(wr+k);
#pragma unroll
        for(int s=0;s<16;++s)
            acc[s] += w4.x*hr[s][k] + w4.y*hr[s][k+1] + w4.z*hr[s][k+2] + w4.w*hr[s][k+3];
    }
    for(int s=0;s<16;++s)
        ws[WS_F1 + (size_t)(b*16+s)*1024 + j] = fmaxf(acc[s],0.0f);
}

__global__ __launch_bounds__(256) void k_ffn2_ln(const float* W2, const float* fb2,
                                                 const float* g2, const float* b2v,
                                                 float* ws, int l){
    __shared__ float f1r[1024]; __shared__ float red[256];
    int bs = blockIdx.x, i = threadIdx.x;
    for(int idx=i; idx<1024; idx+=256) f1r[idx] = ws[WS_F1 + (size_t)bs*1024 + idx];
    __syncthreads();
    const float* wr = W2 + (size_t)(l*256+i)*1024;
    float acc = fb2[l*256+i];
    for(int k=0;k<1024;k+=4){
        float4 w4 = *(const float4*)(wr+k);
        acc += w4.x*f1r[k]+w4.y*f1r[k+1]+w4.z*f1r[k+2]+w4.w*f1r[k+3];
    }
    float x = ws[WS_HB + (size_t)bs*256 + i] + acc;
    red[i]=x; __syncthreads();
    for(int off=128;off>0;off>>=1){ if(i<off) red[i]+=red[i+off]; __syncthreads(); }
    float m = red[0]*(1.0f/256.0f); __syncthreads();
    float d = x-m;
    red[i]=d*d; __syncthreads();
    for(int off=128;off>0;off>>=1){ if(i<off) red[i]+=red[i+off]; __syncthreads(); }
    float v = red[0]*(1.0f/256.0f);
    float y = d / sqrtf(v+1e-5f);
    ws[WS_HB + (size_t)bs*256 + i] = y*g2[l*256+i] + b2v[l*256+i];
}

__global__ __launch_bounds__(256) void k_latent(float* ws){
    int b=blockIdx.x, i=threadIdx.x; float a=0.f;
#pragma unroll
    for(int s=0;s<16;++s) a += ws[WS_HB + (size_t)(b*16+s)*256 + i];
    ws[WS_LAT + (size_t)b*256 + i] = a*(1.0f/16.0f);
}

// ======================= GRU prep ==========================================

__global__ __launch_bounds__(768) void k_gi0(const float* Wih, const float* bih,
                                             float* ws){
    __shared__ float lat[256];
    int b=blockIdx.x, j=threadIdx.x;
    if(j<256) lat[j]=ws[WS_LAT + (size_t)b*256 + j];
    __syncthreads();
    const float* wr = Wih + (size_t)j*256;
    float acc = bih[j];
    for(int k=0;k<256;k+=4){
        float4 w4=*(const float4*)(wr+k);
        acc += w4.x*lat[k]+w4.y*lat[k+1]+w4.z*lat[k+2]+w4.w*lat[k+3];
    }
    ws[WS_GI0 + (size_t)b*768 + j] = acc;
}

// Fused matrix M (1024x256) rows:  0..255 r-gate (A+Whh), 256..511 z-gate
// (A+Whh), 512..767 A_n, 768..1023 Whh_n ; A = Wih @ out_W.
// Output: per-row int8 quantized M (scale rowmax/127) + per-row multiplier
// MS[r] = rowmax/127^2 (h is quantized at fixed scale 127 since |h|<1).
__global__ __launch_bounds__(256) void k_prepm(const float* Wih, const float* Whh,
                                               const float* bih, const float* bhh,
                                               const float* outW, const float* outb,
                                               float* ws){
    __shared__ float wrow[256]; __shared__ float red[256];
    __shared__ signed char q8[256];
    int r=blockIdx.x, c=threadIdx.x;
    bool hasA = (r<768);
    wrow[c] = hasA ? Wih[(size_t)r*256+c] : 0.0f;
    __syncthreads();
    float m;
    if(hasA){
        float a=0.f;
        for(int k=0;k<256;++k) a += wrow[k]*outW[(size_t)k*256+c];
        if(r<512) a += Whh[(size_t)r*256+c];
        m=a;
    } else {
        m = Whh[(size_t)(r-256)*256+c];
    }
    // fused bias constant  C = Wih_row . out_b (+ bih/bhh combos)
    red[c] = wrow[c]*outb[c];
    __syncthreads();
    for(int off=128;off>0;off>>=1){ if(c<off) red[c]+=red[c+off]; __syncthreads(); }
    if(c==0){
        float cv;
        if(r<512)       cv = red[0] + bih[r] + bhh[r];
        else if(r<768)  cv = red[0] + bih[r];
        else            cv = bhh[r-256];
        ws[WS_CV + r] = cv;
    }
    __syncthreads();
    // per-row absmax -> int8 quantization
    red[c] = fabsf(m);
    __syncthreads();
    for(int off=128;off>0;off>>=1){ if(c<off) red[c]=fmaxf(red[c],red[c+off]); __syncthreads(); }
    float rowmax = red[0];
    float inv = rowmax>0.f ? 127.0f/rowmax : 0.0f;
    q8[c] = (signed char)__float2int_rn(m*inv);
    if(c==0) ws[WS_MS + r] = rowmax>0.f ? rowmax*(1.0f/(127.0f*127.0f)) : 0.0f;
    __syncthreads();
    if(c<64){
        uint_t u = ((uint_t)(unsigned char)q8[4*c  ])
                 | ((uint_t)(unsigned char)q8[4*c+1] << 8)
                 | ((uint_t)(unsigned char)q8[4*c+2] << 16)
                 | ((uint_t)(unsigned char)q8[4*c+3] << 24);
        ((uint_t*)ws)[WS_M8 + (size_t)r*64 + c] = u;
    }
}

// ======================= sequential GRU chain ==============================
// 16 blocks (one per batch chain), 512 threads: q = tid&3 (64-col quarter),
// g = tid>>2 (row group).  Thread covers rows g+128*s, s=0..7, ALL resident
// as int8 in 128 arch VGPRs (w8[8][16]).  h int8 double-buffered in LDS
// (4 chunks of 64 B at stride 80 -> 4 distinct bank groups, conflict-free
// b128 broadcast).  Raw s_barrier + lgkmcnt(0): per-step global h-seq
// stores are never vmcnt-drained inside the loop.

__global__ __launch_bounds__(512,2) void k_chain(const float* bhh, float* ws){
    __shared__ alignas(16) signed char h8[2*320];   // 2 x (4 chunks @ 80 B)
    int tid = threadIdx.x;
    int b   = blockIdx.x;
    int q   = tid & 3, g = tid >> 2;

    // all 8 int8 weight slices in registers: 128 dwords / thread
    const uint_t* Mq = (const uint_t*)ws + WS_M8;
    uint_t w8[8][16];
#pragma unroll
    for(int s=0;s<8;++s){
        const uint_t* src = Mq + (size_t)(g + 128*s)*64 + q*16;
#pragma unroll
        for(int k=0;k<16;++k) w8[s][k] = src[k];
    }
    float C8[8], MS8[8];
#pragma unroll
    for(int s=0;s<8;++s){
        C8[s]  = ws[WS_CV + g + 128*s];
        MS8[s] = ws[WS_MS + g + 128*s];
    }

    // step 0: h0 = 0, x0 = latent  ->  gh = bhh  (exact f32 path)
    const float* gi = ws + WS_GI0 + (size_t)b*768;
    float r0 = sigf(gi[g]     + bhh[g]);
    float z0 = sigf(gi[256+g] + bhh[256+g]);
    float n0 = tanh_fast(gi[512+g] + r0*bhh[512+g]);
    float hp0 = (1.0f-z0)*n0;
    float r1 = sigf(gi[128+g] + bhh[128+g]);
    float z1 = sigf(gi[384+g] + bhh[384+g]);
    float n1 = tanh_fast(gi[640+g] + r1*bhh[640+g]);
    float hp1 = (1.0f-z1)*n1;
    float* hsp = ws + WS_HSEQ + (size_t)b*256;
    if(q==0){
        h8[(g>>6)*80     + (g&63)] = (signed char)__float2int_rn(hp0*127.0f);
        h8[(2+(g>>6))*80 + (g&63)] = (signed char)__float2int_rn(hp1*127.0f);
        hsp[g]=hp0; hsp[g+128]=hp1;
    }
    asm volatile("s_waitcnt lgkmcnt(0)" ::: "memory");
    __builtin_amdgcn_s_barrier();
    asm volatile("" ::: "memory");

    int po = 0;
    for(int t=1; t<1028; ++t){
        hsp += 4096;
        // 16 dwords of int8 h for this thread's 64-col quarter
        const uint_t* hb = (const uint_t*)(h8 + po + q*80);
        uint4 x0 = *(const uint4*)(hb);
        uint4 x1 = *(const uint4*)(hb+4);
        uint4 x2 = *(const uint4*)(hb+8);
        uint4 x3 = *(const uint4*)(hb+12);
        uint_t hv[16] = {x0.x,x0.y,x0.z,x0.w, x1.x,x1.y,x1.z,x1.w,
                         x2.x,x2.y,x2.z,x2.w, x3.x,x3.y,x3.z,x3.w};
        int ac[8];
#pragma unroll
        for(int s=0;s<8;++s){
            int a = 0;
#pragma unroll
            for(int k=0;k<16;++k) a = SDOT4(w8[s][k], hv[k], a);
            ac[s] = a;
        }
#pragma unroll
        for(int s=0;s<8;++s) ac[s] = quad_reduce_add_i(ac[s]);
        float f0 = MS8[0]*(float)ac[0] + C8[0];
        float f1 = MS8[1]*(float)ac[1] + C8[1];
        float f2 = MS8[2]*(float)ac[2] + C8[2];
        float f3 = MS8[3]*(float)ac[3] + C8[3];
        float f4 = MS8[4]*(float)ac[4] + C8[4];
        float f5 = MS8[5]*(float)ac[5] + C8[5];
        float f6 = MS8[6]*(float)ac[6] + C8[6];
        float f7 = MS8[7]*(float)ac[7] + C8[7];
        // nonlinearity uniform within quad; stores predicated on q==0
        float rr0 = sigf(f0);
        float zz0 = sigf(f2);
        float nn0 = tanh_fast(f4 + rr0*f6);
        hp0 = (1.0f-zz0)*nn0 + zz0*hp0;
        float rr1 = sigf(f1);
        float zz1 = sigf(f3);
        float nn1 = tanh_fast(f5 + rr1*f7);
        hp1 = (1.0f-zz1)*nn1 + zz1*hp1;
        signed char* hn = h8 + (po^320);
        if(q==0){
            hn[(g>>6)*80     + (g&63)] = (signed char)__float2int_rn(hp0*127.0f);
            hn[(2+(g>>6))*80 + (g&63)] = (signed char)__float2int_rn(hp1*127.0f);
            hsp[g]=hp0; hsp[g+128]=hp1;
        }
        asm volatile("s_waitcnt lgkmcnt(0)" ::: "memory");
        __builtin_amdgcn_s_barrier();
        asm volatile("" ::: "memory");
        po ^= 320;
    }
}

// ======================= epilogue GEMM =====================================
// OUT[b][t*256+j] = sum_c out_W[j][c]*HSEQ[t][b][c] + out_b[j]
__global__ __launch_bounds__(256) void k_epi(const float* outW, const float* outb,
                                             const float* ws, float* out){
    __shared__ float ht[16][256];
    int t = blockIdx.x, j = threadIdx.x;
    for(int idx=j; idx<4096; idx+=256)
        ht[idx>>8][idx&255] = ws[WS_HSEQ + (size_t)t*4096 + idx];
    __syncthreads();
    const float* wr = outW + (size_t)j*256;
    float bias = outb[j];
    float acc[16];
#pragma unroll
    for(int bb=0;bb<16;++bb) acc[bb]=bias;
    for(int k=0;k<256;k+=4){
        float4 w4 = *(const float4*)(wr+k);
#pragma unroll
        for(int bb=0;bb<16;++bb)
            acc[bb] += w4.x*ht[bb][k]+w4.y*ht[bb][k+1]+w4.z*ht[bb][k+2]+w4.w*ht[bb][k+3];
    }
#pragma unroll
    for(int bb=0;bb<16;++bb)
        out[(size_t)bb*263168 + (size_t)t*256 + j] = acc[bb];
}

// ======================= launch ============================================

extern "C" void kernel_launch(void* const* d_in, const int* in_sizes, int n_in,
                              void* d_out, int out_size, void* d_ws, size_t ws_size,
                              hipStream_t stream){
    const float* gs   = (const float*)d_in[0];
    const float* eW   = (const float*)d_in[1];
    const float* eb   = (const float*)d_in[2];
    const float* qkvW = (const float*)d_in[3];
    const float* qkvb = (const float*)d_in[4];
    const float* aoW  = (const float*)d_in[5];
    const float* aob  = (const float*)d_in[6];
    const float* g1   = (const float*)d_in[7];
    const float* b1   = (const float*)d_in[8];
    const float* g2   = (const float*)d_in[9];
    const float* b2   = (const float*)d_in[10];
    const float* W1   = (const float*)d_in[11];
    const float* fb1  = (const float*)d_in[12];
    const float* W2   = (const float*)d_in[13];
    const float* fb2  = (const float*)d_in[14];
    const float* Wih  = (const float*)d_in[15];
    const float* Whh  = (const float*)d_in[16];
    const float* bih  = (const float*)d_in[17];
    const float* bhh  = (const float*)d_in[18];
    const float* outW = (const float*)d_in[19];
    const float* outb = (const float*)d_in[20];
    float* ws  = (float*)d_ws;
    float* out = (float*)d_out;

    k_embed<<<256,256,0,stream>>>(gs,eW,eb,ws);
    for(int l=0;l<2;++l){
        k_qkv    <<<dim3(16,3),256,0,stream>>>(qkvW,qkvb,ws,l);
        k_attn   <<<64,256,0,stream>>>(ws);
        k_ao_ln  <<<256,256,0,stream>>>(aoW,aob,g1,b1,ws,l);
        k_ffn1   <<<dim3(16,4),256,0,stream>>>(W1,fb1,ws,l);
        k_ffn2_ln<<<256,256,0,stream>>>(W2,fb2,g2,b2,ws,l);
    }
    k_latent<<<16,256,0,stream>>>(ws);
    k_gi0   <<<16,768,0,stream>>>(Wih,bih,ws);
    k_prepm <<<1024,256,0,stream>>>(Wih,Whh,bih,bhh,outW,outb,ws);
    k_chain <<<16,512,0,stream>>>(bhh,ws);
    k_epi   <<<1028,256,0,stream>>>(outW,outb,ws,out);
}

// Round 2
// 1126.641 us; speedup vs baseline: 1.8876x; 1.3530x over previous
//
#include <hip/hip_runtime.h>

// ---------------------------------------------------------------------------
// GenomeDecoder: transformer encoder (tiny) -> 1028 sequential GRU steps ->
// output chunks.  Chunk feedback folded into recurrence (A = Wih@out_W
// absorbed), r/z gate rows pre-summed -> one 1024x256 matvec per step.
// R4: matvec moved to the MATRIX pipe: mfma_i32_16x16x64_i8 with h broadcast
// into all 16 A-rows (rows identical -> D[m][n]=y[n] for all m, no masking).
// Per wave: 8 N-tiles (r/z/An/Whhn x 2 halves of its 32-elem h slice) x
// 4 K-tiles = 32 MFMA/step, replacing 128 v_dot4 + DPP reduce + AGPR copies
// (MFMA sources AGPRs natively).  Gates lane-local via C/D col=lane&15
// layout; fast exp2/rcp gates (no IEEE div).  Int32 accumulation exact ->
// same quantization error as R3 (absmax ~3e-4).
// ---------------------------------------------------------------------------

typedef unsigned int uint_t;
typedef int v4i __attribute__((ext_vector_type(4)));

// ---- workspace layout (4-byte slot indices) ----
static constexpr size_t WS_HB   = 0;        // 16*16*256
static constexpr size_t WS_QKV  = 65536;    // 16*16*768
static constexpr size_t WS_AO   = 262144;   // 16*16*256
static constexpr size_t WS_F1   = 327680;   // 16*16*1024
static constexpr size_t WS_LAT  = 589824;   // 16*256
static constexpr size_t WS_GI0  = 593920;   // 16*768
static constexpr size_t WS_CV   = 606208;   // 1024 fused-bias consts
static constexpr size_t WS_MS   = 607232;   // 1024 per-row scales (rowmax/127^2)
static constexpr size_t WS_M8   = 608256;   // 1024*64 dwords of packed int8 M
static constexpr size_t WS_HSEQ = 673792;   // 1028*16*256 floats

// fast gates: v_exp_f32 is 2^x, v_rcp_f32 ~1ulp -> negligible vs int8 quant
__device__ inline float sigf(float x){
    return __builtin_amdgcn_rcpf(1.0f + __builtin_amdgcn_exp2f(-1.442695041f*x));
}
__device__ inline float tanh_fast(float x){
    // tanh(x) = 1 - 2/(exp2(2x*log2e)+1)
    return 1.0f - 2.0f*__builtin_amdgcn_rcpf(1.0f + __builtin_amdgcn_exp2f(2.885390082f*x));
}

// ======================= transformer front-end =============================

__global__ __launch_bounds__(256) void k_embed(const float* gs, const float* eW,
                                               const float* eb, float* ws){
    int bs = blockIdx.x;            // b*16+s
    int i  = threadIdx.x;
    const float* g = gs + bs*16;
    float acc = eb[i];
#pragma unroll
    for(int d=0; d<16; ++d) acc += g[d]*eW[i*16+d];
    ws[WS_HB + (size_t)bs*256 + i] = acc;
}

__global__ __launch_bounds__(256) void k_qkv(const float* qkvW, const float* qkvb,
                                             float* ws, int l){
    __shared__ float hr[16][256];
    int b = blockIdx.x, jc = blockIdx.y;
    for(int idx=threadIdx.x; idx<4096; idx+=256)
        hr[idx>>8][idx&255] = ws[WS_HB + (size_t)(b*16+(idx>>8))*256 + (idx&255)];
    __syncthreads();
    int j = jc*256 + threadIdx.x;
    float bias = qkvb[l*768 + j];
    float acc[16];
#pragma unroll
    for(int s=0;s<16;++s) acc[s]=bias;
    const float* wr = qkvW + (size_t)(l*768 + j)*256;
    for(int k=0;k<256;k+=4){
        float4 w4 = *(const float4*)(wr+k);
#pragma unroll
        for(int s=0;s<16;++s)
            acc[s] += w4.x*hr[s][k] + w4.y*hr[s][k+1] + w4.z*hr[s][k+2] + w4.w*hr[s][k+3];
    }
    for(int s=0;s<16;++s) ws[WS_QKV + (size_t)(b*16+s)*768 + j] = acc[s];
}

__global__ __launch_bounds__(256) void k_attn(float* ws){
    __shared__ float ql[16][64], kl[16][64], vl[16][64], sc[16][16];
    int b = blockIdx.x>>2, hh = blockIdx.x&3;
    for(int idx=threadIdx.x; idx<1024; idx+=256){
        int s_=idx>>6, d=idx&63;
        const float* base = &ws[WS_QKV + (size_t)(b*16+s_)*768 + hh*64 + d];
        ql[s_][d]=base[0]; kl[s_][d]=base[256]; vl[s_][d]=base[512];
    }
    __syncthreads();
    int s = threadIdx.x>>4, t = threadIdx.x&15;
    float a=0.f;
#pragma unroll
    for(int d=0; d<64; ++d) a += ql[s][d]*kl[t][d];
    sc[s][t] = a*0.125f;
    __syncthreads();
    if(threadIdx.x<16){
        int r=threadIdx.x;
        float m=-1e30f;
#pragma unroll
        for(int tt=0;tt<16;++tt) m=fmaxf(m,sc[r][tt]);
        float e[16]; float sum=0.f;
#pragma unroll
        for(int tt=0;tt<16;++tt){ e[tt]=__expf(sc[r][tt]-m); sum+=e[tt]; }
        float inv=1.0f/sum;
#pragma unroll
        for(int tt=0;tt<16;++tt) sc[r][tt]=e[tt]*inv;
    }
    __syncthreads();
    int dg = (threadIdx.x&15)*4;
#pragma unroll
    for(int dd=0;dd<4;++dd){
        int d = dg+dd; float o=0.f;
#pragma unroll
        for(int tt=0;tt<16;++tt) o += sc[s][tt]*vl[tt][d];
        ws[WS_AO + (size_t)(b*16+s)*256 + hh*64 + d] = o;
    }
}

__global__ __launch_bounds__(256) void k_ao_ln(const float* aoW, const float* aob,
                                               const float* g1, const float* b1,
                                               float* ws, int l){
    __shared__ float ao[256]; __shared__ float red[256];
    int bs = blockIdx.x, i = threadIdx.x;
    ao[i] = ws[WS_AO + (size_t)bs*256 + i];
    __syncthreads();
    const float* wr = aoW + (size_t)(l*256+i)*256;
    float acc = aob[l*256+i];
    for(int k=0;k<256;k+=4){
        float4 w4 = *(const float4*)(wr+k);
        acc += w4.x*ao[k]+w4.y*ao[k+1]+w4.z*ao[k+2]+w4.w*ao[k+3];
    }
    float x = ws[WS_HB + (size_t)bs*256 + i] + acc;
    red[i]=x; __syncthreads();
    for(int off=128;off>0;off>>=1){ if(i<off) red[i]+=red[i+off]; __syncthreads(); }
    float m = red[0]*(1.0f/256.0f); __syncthreads();
    float d = x-m;
    red[i]=d*d; __syncthreads();
    for(int off=128;off>0;off>>=1){ if(i<off) red[i]+=red[i+off]; __syncthreads(); }
    float v = red[0]*(1.0f/256.0f);
    float y = d / sqrtf(v+1e-5f);
    ws[WS_HB + (size_t)bs*256 + i] = y*g1[l*256+i] + b1[l*256+i];
}

__global__ __launch_bounds__(256) void k_ffn1(const float* W1, const float* fb1,
                                              float* ws, int l){
    __shared__ float hr[16][256];
    int b = blockIdx.x, jc = blockIdx.y;
    for(int idx=threadIdx.x; idx<4096; idx+=256)
        hr[idx>>8][idx&255] = ws[WS_HB + (size_t)(b*16+(idx>>8))*256 + (idx&255)];
    __syncthreads();
    int j = jc*256 + threadIdx.x;
    float bias = fb1[l*1024+j];
    float acc[16];
#pragma unroll
    for(int s=0;s<16;++s) acc[s]=bias;
    const float* wr = W1 + (size_t)(l*1024+j)*256;
    for(int k=0;k<256;k+=4){
        float4 w4 = *(const float4*)(wr+k);
#pragma unroll
        for(int s=0;s<16;++s)
            acc[s] += w4.x*hr[s][k] + w4.y*hr[s][k+1] + w4.z*hr[s][k+2] + w4.w*hr[s][k+3];
    }
    for(int s=0;s<16;++s)
        ws[WS_F1 + (size_t)(b*16+s)*1024 + j] = fmaxf(acc[s],0.0f);
}

__global__ __launch_bounds__(256) void k_ffn2_ln(const float* W2, const float* fb2,
                                                 const float* g2, const float* b2v,
                                                 float* ws, int l){
    __shared__ float f1r[1024]; __shared__ float red[256];
    int bs = blockIdx.x, i = threadIdx.x;
    for(int idx=i; idx<1024; idx+=256) f1r[idx] = ws[WS_F1 + (size_t)bs*1024 + idx];
    __syncthreads();
    const float* wr = W2 + (size_t)(l*256+i)*1024;
    float acc = fb2[l*256+i];
    for(int k=0;k<1024;k+=4){
        float4 w4 = *(const float4*)(wr+k);
        acc += w4.x*f1r[k]+w4.y*f1r[k+1]+w4.z*f1r[k+2]+w4.w*f1r[k+3];
    }
    float x = ws[WS_HB + (size_t)bs*256 + i] + acc;
    red[i]=x; __syncthreads();
    for(int off=128;off>0;off>>=1){ if(i<off) red[i]+=red[i+off]; __syncthreads(); }
    float m = red[0]*(1.0f/256.0f); __syncthreads();
    float d = x-m;
    red[i]=d*d; __syncthreads();
    for(int off=128;off>0;off>>=1){ if(i<off) red[i]+=red[i+off]; __syncthreads(); }
    float v = red[0]*(1.0f/256.0f);
    float y = d / sqrtf(v+1e-5f);
    ws[WS_HB + (size_t)bs*256 + i] = y*g2[l*256+i] + b2v[l*256+i];
}

__global__ __launch_bounds__(256) void k_latent(float* ws){
    int b=blockIdx.x, i=threadIdx.x; float a=0.f;
#pragma unroll
    for(int s=0;s<16;++s) a += ws[WS_HB + (size_t)(b*16+s)*256 + i];
    ws[WS_LAT + (size_t)b*256 + i] = a*(1.0f/16.0f);
}

// ======================= GRU prep ==========================================

__global__ __launch_bounds__(768) void k_gi0(const float* Wih, const float* bih,
                                             float* ws){
    __shared__ float lat[256];
    int b=blockIdx.x, j=threadIdx.x;
    if(j<256) lat[j]=ws[WS_LAT + (size_t)b*256 + j];
    __syncthreads();
    const float* wr = Wih + (size_t)j*256;
    float acc = bih[j];
    for(int k=0;k<256;k+=4){
        float4 w4=*(const float4*)(wr+k);
        acc += w4.x*lat[k]+w4.y*lat[k+1]+w4.z*lat[k+2]+w4.w*lat[k+3];
    }
    ws[WS_GI0 + (size_t)b*768 + j] = acc;
}

// Fused matrix M (1024x256) rows:  0..255 r-gate (A+Whh), 256..511 z-gate
// (A+Whh), 512..767 A_n, 768..1023 Whh_n ; A = Wih @ out_W.
// Output: per-row int8 quantized M (scale rowmax/127) + per-row multiplier
// MS[r] = rowmax/127^2 (h is quantized at fixed scale 127 since |h|<1).
__global__ __launch_bounds__(256) void k_prepm(const float* Wih, const float* Whh,
                                               const float* bih, const float* bhh,
                                               const float* outW, const float* outb,
                                               float* ws){
    __shared__ float wrow[256]; __shared__ float red[256];
    __shared__ signed char q8[256];
    int r=blockIdx.x, c=threadIdx.x;
    bool hasA = (r<768);
    wrow[c] = hasA ? Wih[(size_t)r*256+c] : 0.0f;
    __syncthreads();
    float m;
    if(hasA){
        float a=0.f;
        for(int k=0;k<256;++k) a += wrow[k]*outW[(size_t)k*256+c];
        if(r<512) a += Whh[(size_t)r*256+c];
        m=a;
    } else {
        m = Whh[(size_t)(r-256)*256+c];
    }
    // fused bias constant  C = Wih_row . out_b (+ bih/bhh combos)
    red[c] = wrow[c]*outb[c];
    __syncthreads();
    for(int off=128;off>0;off>>=1){ if(c<off) red[c]+=red[c+off]; __syncthreads(); }
    if(c==0){
        float cv;
        if(r<512)       cv = red[0] + bih[r] + bhh[r];
        else if(r<768)  cv = red[0] + bih[r];
        else            cv = bhh[r-256];
        ws[WS_CV + r] = cv;
    }
    __syncthreads();
    // per-row absmax -> int8 quantization
    red[c] = fabsf(m);
    __syncthreads();
    for(int off=128;off>0;off>>=1){ if(c<off) red[c]=fmaxf(red[c],red[c+off]); __syncthreads(); }
    float rowmax = red[0];
    float inv = rowmax>0.f ? 127.0f/rowmax : 0.0f;
    q8[c] = (signed char)__float2int_rn(m*inv);
    if(c==0) ws[WS_MS + r] = rowmax>0.f ? rowmax*(1.0f/(127.0f*127.0f)) : 0.0f;
    __syncthreads();
    if(c<64){
        uint_t u = ((uint_t)(unsigned char)q8[4*c  ])
                 | ((uint_t)(unsigned char)q8[4*c+1] << 8)
                 | ((uint_t)(unsigned char)q8[4*c+2] << 16)
                 | ((uint_t)(unsigned char)q8[4*c+3] << 24);
        ((uint_t*)ws)[WS_M8 + (size_t)r*64 + c] = u;
    }
}

// ======================= sequential GRU chain ==============================
// 16 blocks (one per batch chain), 512 threads = 8 waves.  Wave w owns h
// slice [w*32, w*32+32): 8 N-tiles (4 gate slices x 2 halves) x 4 K-tiles,
// each a mfma_i32_16x16x64_i8.  A operand = h int8 broadcast into all 16
// rows (every lane loads the same 16 h-bytes of its K-chunk l>>4) -> every
// D row equals y, lane holds y[base + (lane&15)] -> gates fully lane-local.
// h double-buffered in LDS (2x256B); raw s_barrier + lgkmcnt-only wait so
// the per-step global h store never drains vmcnt on the critical path.

__global__ __launch_bounds__(512,2) void k_chain(const float* bhh, float* ws){
    __shared__ alignas(16) signed char h8[2][256];
    int tid = threadIdx.x;
    int b   = blockIdx.x;
    int l   = tid & 63;          // lane in wave
    int w   = tid >> 6;          // wave 0..7
    int col = l & 15;
    int grp = l >> 4;            // K-chunk / store group
    int g0  = w*32 + col;        // h index (half 0); half 1 = g0+16

    const uint_t* Mdw = (const uint_t*)ws + WS_M8;

    // B fragments: f = s*2+half (s: 0=r 1=z 2=An 3=Whhn), kt = 0..3
    // lane holds M8[row = s*256 + w*32 + half*16 + col][k = kt*64 + grp*16 ..+15]
    v4i wf[8][4];
    float C8[8], MS8[8];
#pragma unroll
    for(int s=0;s<4;++s){
#pragma unroll
        for(int half=0; half<2; ++half){
            int f = s*2 + half;
            int row = s*256 + w*32 + half*16 + col;
            const uint_t* src = Mdw + (size_t)row*64 + grp*4;
#pragma unroll
            for(int kt=0;kt<4;++kt)
                wf[f][kt] = *(const v4i*)(src + kt*16);
            C8[f]  = ws[WS_CV + row];
            MS8[f] = ws[WS_MS + row];
        }
    }

    // step 0: h0 = 0, x0 = latent  ->  gh = bhh  (exact f32 path)
    const float* gi = ws + WS_GI0 + (size_t)b*768;
    int g1 = g0 + 16;
    float r0 = sigf(gi[g0]     + bhh[g0]);
    float z0 = sigf(gi[256+g0] + bhh[256+g0]);
    float n0 = tanh_fast(gi[512+g0] + r0*bhh[512+g0]);
    float hp0 = (1.0f-z0)*n0;
    float r1 = sigf(gi[g1]     + bhh[g1]);
    float z1 = sigf(gi[256+g1] + bhh[256+g1]);
    float n1 = tanh_fast(gi[512+g1] + r1*bhh[512+g1]);
    float hp1 = (1.0f-z1)*n1;

    float* hsp = ws + WS_HSEQ + (size_t)b*256;
    if(grp < 2){
        float v = grp ? hp1 : hp0;
        h8[0][w*32 + (l&31)] = (signed char)__float2int_rn(v*127.0f);
        hsp[w*32 + (l&31)] = v;
    }
    asm volatile("s_waitcnt lgkmcnt(0)" ::: "memory");
    __builtin_amdgcn_s_barrier();
    asm volatile("" ::: "memory");

    const v4i vzero = {0,0,0,0};
    int po = 0;
    for(int t=1; t<1028; ++t){
        hsp += 4096;
        // A fragments: broadcast h (identical across lanes of a K-chunk group)
        v4i af[4];
#pragma unroll
        for(int kt=0;kt<4;++kt)
            af[kt] = *(const v4i*)&h8[po][kt*64 + grp*16];
        v4i acc[8];
#pragma unroll
        for(int f=0;f<8;++f){
            acc[f] = __builtin_amdgcn_mfma_i32_16x16x64_i8(af[0], wf[f][0], vzero, 0,0,0);
#pragma unroll
            for(int kt=1;kt<4;++kt)
                acc[f] = __builtin_amdgcn_mfma_i32_16x16x64_i8(af[kt], wf[f][kt], acc[f], 0,0,0);
        }
        // every lane: full gate set for g0 (even f) and g1 (odd f)
        float yr0 = MS8[0]*(float)acc[0][0] + C8[0];
        float yr1 = MS8[1]*(float)acc[1][0] + C8[1];
        float yz0 = MS8[2]*(float)acc[2][0] + C8[2];
        float yz1 = MS8[3]*(float)acc[3][0] + C8[3];
        float yn0 = MS8[4]*(float)acc[4][0] + C8[4];
        float yn1 = MS8[5]*(float)acc[5][0] + C8[5];
        float yh0 = MS8[6]*(float)acc[6][0] + C8[6];
        float yh1 = MS8[7]*(float)acc[7][0] + C8[7];
        float rr0 = sigf(yr0), rr1 = sigf(yr1);
        float zz0 = sigf(yz0), zz1 = sigf(yz1);
        float nn0 = tanh_fast(yn0 + rr0*yh0);
        float nn1 = tanh_fast(yn1 + rr1*yh1);
        hp0 = (1.0f-zz0)*nn0 + zz0*hp0;
        hp1 = (1.0f-zz1)*nn1 + zz1*hp1;
        if(grp < 2){
            float v = grp ? hp1 : hp0;
            h8[po^1][w*32 + (l&31)] = (signed char)__float2int_rn(v*127.0f);
            hsp[w*32 + (l&31)] = v;
        }
        asm volatile("s_waitcnt lgkmcnt(0)" ::: "memory");
        __builtin_amdgcn_s_barrier();
        asm volatile("" ::: "memory");
        po ^= 1;
    }
}

// ======================= epilogue GEMM =====================================
// OUT[b][t*256+j] = sum_c out_W[j][c]*HSEQ[t][b][c] + out_b[j]
__global__ __launch_bounds__(256) void k_epi(const float* outW, const float* outb,
                                             const float* ws, float* out){
    __shared__ float ht[16][256];
    int t = blockIdx.x, j = threadIdx.x;
    for(int idx=j; idx<4096; idx+=256)
        ht[idx>>8][idx&255] = ws[WS_HSEQ + (size_t)t*4096 + idx];
    __syncthreads();
    const float* wr = outW + (size_t)j*256;
    float bias = outb[j];
    float acc[16];
#pragma unroll
    for(int bb=0;bb<16;++bb) acc[bb]=bias;
    for(int k=0;k<256;k+=4){
        float4 w4 = *(const float4*)(wr+k);
#pragma unroll
        for(int bb=0;bb<16;++bb)
            acc[bb] += w4.x*ht[bb][k]+w4.y*ht[bb][k+1]+w4.z*ht[bb][k+2]+w4.w*ht[bb][k+3];
    }
#pragma unroll
    for(int bb=0;bb<16;++bb)
        out[(size_t)bb*263168 + (size_t)t*256 + j] = acc[bb];
}

// ======================= launch ============================================

extern "C" void kernel_launch(void* const* d_in, const int* in_sizes, int n_in,
                              void* d_out, int out_size, void* d_ws, size_t ws_size,
                              hipStream_t stream){
    const float* gs   = (const float*)d_in[0];
    const float* eW   = (const float*)d_in[1];
    const float* eb   = (const float*)d_in[2];
    const float* qkvW = (const float*)d_in[3];
    const float* qkvb = (const float*)d_in[4];
    const float* aoW  = (const float*)d_in[5];
    const float* aob  = (const float*)d_in[6];
    const float* g1   = (const float*)d_in[7];
    const float* b1   = (const float*)d_in[8];
    const float* g2   = (const float*)d_in[9];
    const float* b2   = (const float*)d_in[10];
    const float* W1   = (const float*)d_in[11];
    const float* fb1  = (const float*)d_in[12];
    const float* W2   = (const float*)d_in[13];
    const float* fb2  = (const float*)d_in[14];
    const float* Wih  = (const float*)d_in[15];
    const float* Whh  = (const float*)d_in[16];
    const float* bih  = (const float*)d_in[17];
    const float* bhh  = (const float*)d_in[18];
    const float* outW = (const float*)d_in[19];
    const float* outb = (const float*)d_in[20];
    float* ws  = (float*)d_ws;
    float* out = (float*)d_out;

    k_embed<<<256,256,0,stream>>>(gs,eW,eb,ws);
    for(int l=0;l<2;++l){
        k_qkv    <<<dim3(16,3),256,0,stream>>>(qkvW,qkvb,ws,l);
        k_attn   <<<64,256,0,stream>>>(ws);
        k_ao_ln  <<<256,256,0,stream>>>(aoW,aob,g1,b1,ws,l);
        k_ffn1   <<<dim3(16,4),256,0,stream>>>(W1,fb1,ws,l);
        k_ffn2_ln<<<256,256,0,stream>>>(W2,fb2,g2,b2,ws,l);
    }
    k_latent<<<16,256,0,stream>>>(ws);
    k_gi0   <<<16,768,0,stream>>>(Wih,bih,ws);
    k_prepm <<<1024,256,0,stream>>>(Wih,Whh,bih,bhh,outW,outb,ws);
    k_chain <<<16,512,0,stream>>>(bhh,ws);
    k_epi   <<<1028,256,0,stream>>>(outW,outb,ws,out);
}